// Round 1
// baseline (419.300 us; speedup 1.0000x reference)
//
#include <hip/hip_runtime.h>

#define HW      4096
#define WIDTH   64
#define C_MAIN  512
#define C_F     576
#define HO      62
#define KPATCH  3844   // 62*62
#define ALPHA_W 0.6f
#define SEM_W   0.5f
#define EPS_V   1e-5f

// ---------------------------------------------------------------------------
// 1. Instance-norm projection + semantic concat:  cFf/sFf [576][4096]
// ---------------------------------------------------------------------------
__global__ __launch_bounds__(256) void project_kernel(
    const float* __restrict__ cF, const float* __restrict__ sF,
    const float* __restrict__ cSem, const float* __restrict__ sSem,
    float* __restrict__ cFf, float* __restrict__ sFf) {
  int bid = blockIdx.x;            // 0..1151
  int tensor = bid / C_F;          // 0: content, 1: style
  int c = bid - tensor * C_F;
  float* dst = (tensor ? sFf : cFf) + (size_t)c * HW;
  int t = threadIdx.x;

  if (c >= C_MAIN) {               // semantic channel: just scale by 0.5
    const float* src = (tensor ? sSem : cSem) + (size_t)(c - C_MAIN) * HW;
    for (int p = t * 4; p < HW; p += 256 * 4) {
      float4 v = *(const float4*)(src + p);
      v.x *= SEM_W; v.y *= SEM_W; v.z *= SEM_W; v.w *= SEM_W;
      *(float4*)(dst + p) = v;
    }
    return;
  }

  const float* src = (tensor ? sF : cF) + (size_t)c * HW;
  float4 vals[4];
  float sum = 0.f, sumsq = 0.f;
#pragma unroll
  for (int i = 0; i < 4; ++i) {
    vals[i] = *(const float4*)(src + (i * 256 + t) * 4);
    sum   += vals[i].x + vals[i].y + vals[i].z + vals[i].w;
    sumsq += vals[i].x * vals[i].x + vals[i].y * vals[i].y +
             vals[i].z * vals[i].z + vals[i].w * vals[i].w;
  }
#pragma unroll
  for (int off = 32; off; off >>= 1) {
    sum   += __shfl_down(sum, off, 64);
    sumsq += __shfl_down(sumsq, off, 64);
  }
  __shared__ float ls[10];
  int lane = t & 63, wv = t >> 6;
  if (lane == 0) { ls[wv] = sum; ls[4 + wv] = sumsq; }
  __syncthreads();
  if (t == 0) {
    float s  = ls[0] + ls[1] + ls[2] + ls[3];
    float sq = ls[4] + ls[5] + ls[6] + ls[7];
    float mean = s / 4096.f;
    float var  = (sq - 4096.f * mean * mean) / 4095.f;   // ddof=1
    ls[8] = mean;
    ls[9] = 1.f / sqrtf(var + EPS_V);
  }
  __syncthreads();
  float mean = ls[8], rstd = ls[9];
#pragma unroll
  for (int i = 0; i < 4; ++i) {
    float4 v = vals[i];
    v.x = (v.x - mean) * rstd; v.y = (v.y - mean) * rstd;
    v.z = (v.z - mean) * rstd; v.w = (v.w - mean) * rstd;
    *(float4*)(dst + (i * 256 + t) * 4) = v;
  }
}

// ---------------------------------------------------------------------------
// 2. fp32 GEMM: M[a][u] = sum_k cFf[k][a] * sFf[k][u]   (4096x4096, K=576)
// ---------------------------------------------------------------------------
__global__ __launch_bounds__(256) void gemm_kernel(
    const float* __restrict__ A, const float* __restrict__ B,
    float* __restrict__ M) {
  __shared__ float As[16][64];
  __shared__ float Bs[16][64];
  int a0 = blockIdx.x * 64;
  int u0 = blockIdx.y * 64;
  int t = threadIdx.x;
  int tx = t & 15, ty = t >> 4;
  int lrow = t >> 4;           // k-row within tile (0..15)
  int lcol = (t & 15) * 4;     // col within tile

  float acc[4][4] = {};
  for (int k0 = 0; k0 < C_F; k0 += 16) {
    float4 av = *(const float4*)(A + (size_t)(k0 + lrow) * HW + a0 + lcol);
    float4 bv = *(const float4*)(B + (size_t)(k0 + lrow) * HW + u0 + lcol);
    __syncthreads();
    *(float4*)&As[lrow][lcol] = av;
    *(float4*)&Bs[lrow][lcol] = bv;
    __syncthreads();
#pragma unroll
    for (int kk = 0; kk < 16; ++kk) {
      float a4[4], b4[4];
      *(float4*)a4 = *(const float4*)&As[kk][ty * 4];
      *(float4*)b4 = *(const float4*)&Bs[kk][tx * 4];
#pragma unroll
      for (int i = 0; i < 4; ++i)
#pragma unroll
        for (int j = 0; j < 4; ++j) acc[i][j] += a4[i] * b4[j];
    }
  }
#pragma unroll
  for (int i = 0; i < 4; ++i) {
    float4 v = {acc[i][0], acc[i][1], acc[i][2], acc[i][3]};
    *(float4*)(M + (size_t)(a0 + ty * 4 + i) * HW + u0 + tx * 4) = v;
  }
}

// ---------------------------------------------------------------------------
// 3a. q[u] = sum_c sFf[c][u]^2
// ---------------------------------------------------------------------------
__global__ __launch_bounds__(256) void colsumsq_kernel(
    const float* __restrict__ sFf, float* __restrict__ q) {
  int u = blockIdx.x * 256 + threadIdx.x;
  float s = 0.f;
  for (int c = 0; c < C_F; ++c) {
    float v = sFf[(size_t)c * HW + u];
    s += v * v;
  }
  q[u] = s;
}

// 3b. rnorm[k] = 1/(sqrt(3x3 box of q) + 1e-7)
__global__ __launch_bounds__(256) void rnorm_kernel(
    const float* __restrict__ q, float* __restrict__ rnorm) {
  int k = blockIdx.x * 256 + threadIdx.x;
  if (k >= KPATCH) return;
  int ky = k / HO, kx = k - ky * HO;
  float s = 0.f;
#pragma unroll
  for (int i = 0; i < 3; ++i)
#pragma unroll
    for (int j = 0; j < 3; ++j) s += q[(ky + i) * WIDTH + kx + j];
  rnorm[k] = 1.f / (sqrtf(s) + 1e-7f);
}

// ---------------------------------------------------------------------------
// 4. argmax over styles: one block per content position
// ---------------------------------------------------------------------------
__global__ __launch_bounds__(256) void argmax_kernel(
    const float* __restrict__ M, const float* __restrict__ rnorm,
    int* __restrict__ idx) {
  int bid = blockIdx.x;           // 0..3843
  int y = bid / HO, x = bid - y * HO;
  const float* base[9];
#pragma unroll
  for (int i = 0; i < 3; ++i)
#pragma unroll
    for (int j = 0; j < 3; ++j)
      base[i * 3 + j] = M + (size_t)((y + i) * WIDTH + x + j) * HW + i * WIDTH + j;

  float best = -1e30f;
  int bestk = 0;
  for (int k = threadIdx.x; k < KPATCH; k += 256) {
    int ky = k / HO;
    int u = k + 2 * ky;           // ky*64 + kx
    float s = base[0][u] + base[1][u] + base[2][u] +
              base[3][u] + base[4][u] + base[5][u] +
              base[6][u] + base[7][u] + base[8][u];
    float v = s * rnorm[k];
    if (v > best) { best = v; bestk = k; }   // strict > keeps lowest k
  }
  __shared__ float sv[256];
  __shared__ int   sk[256];
  sv[threadIdx.x] = best; sk[threadIdx.x] = bestk;
  __syncthreads();
  for (int off = 128; off; off >>= 1) {
    if (threadIdx.x < off) {
      float ov = sv[threadIdx.x + off]; int ok = sk[threadIdx.x + off];
      if (ov > sv[threadIdx.x] ||
          (ov == sv[threadIdx.x] && ok < sk[threadIdx.x])) {
        sv[threadIdx.x] = ov; sk[threadIdx.x] = ok;
      }
    }
    __syncthreads();
  }
  if (threadIdx.x == 0) idx[bid] = sk[0];
}

// ---------------------------------------------------------------------------
// 5. transpose sF [c][pix] -> sFt [pix][c]
// ---------------------------------------------------------------------------
__global__ __launch_bounds__(256) void transpose_kernel(
    const float* __restrict__ sF, float* __restrict__ sFt) {
  __shared__ float tile[32][33];
  int p0 = blockIdx.x * 32;
  int c0 = blockIdx.y * 32;
  int tx = threadIdx.x, ty = threadIdx.y;   // (32,8)
  for (int r = ty; r < 32; r += 8)
    tile[r][tx] = sF[(size_t)(c0 + r) * HW + p0 + tx];
  __syncthreads();
  for (int r = ty; r < 32; r += 8)
    sFt[(size_t)(p0 + r) * C_MAIN + c0 + tx] = tile[tx][r];
}

// ---------------------------------------------------------------------------
// 6. gather selected patches, overlap-add in [pix][c]
// ---------------------------------------------------------------------------
__global__ __launch_bounds__(256) void gather_kernel(
    const float* __restrict__ sFt, const int* __restrict__ idx,
    float* __restrict__ tmp) {
  __shared__ int srcs[9];
  __shared__ int nv;
  int pix = blockIdx.x;
  int h = pix >> 6, w = pix & 63;
  if (threadIdx.x == 0) {
    int n = 0;
    for (int i = 0; i < 3; ++i)
      for (int j = 0; j < 3; ++j) {
        int y = h - i, x = w - j;
        if (y >= 0 && y < HO && x >= 0 && x < HO) {
          int k = idx[y * HO + x];
          int ky = k / HO, kx = k - ky * HO;
          srcs[n++] = (ky + i) * WIDTH + kx + j;
        }
      }
    nv = n;
  }
  __syncthreads();
  int n = nv;
  for (int c = threadIdx.x; c < C_MAIN; c += 256) {
    float acc = 0.f;
    for (int s = 0; s < n; ++s) acc += sFt[(size_t)srcs[s] * C_MAIN + c];
    tmp[(size_t)pix * C_MAIN + c] = acc;
  }
}

// ---------------------------------------------------------------------------
// 7. blend + transpose back:  out[c][pix] = 0.6*tmp[pix][c]/cnt + 0.4*cF
// ---------------------------------------------------------------------------
__global__ __launch_bounds__(256) void blend_kernel(
    const float* __restrict__ tmp, const float* __restrict__ cF,
    float* __restrict__ out) {
  __shared__ float tile[32][33];
  int p0 = blockIdx.x * 32;
  int c0 = blockIdx.y * 32;
  int tx = threadIdx.x, ty = threadIdx.y;   // (32,8)
  for (int r = ty; r < 32; r += 8)
    tile[r][tx] = tmp[(size_t)(p0 + r) * C_MAIN + c0 + tx];
  __syncthreads();
  for (int r = ty; r < 32; r += 8) {
    int pix = p0 + tx;
    int h = pix >> 6, w = pix & 63;
    int nh = min(2, h) - max(0, h - 61) + 1;
    int nw = min(2, w) - max(0, w - 61) + 1;
    float inv_cnt = 1.f / (float)(nh * nw);
    int c = c0 + r;
    out[(size_t)c * HW + pix] =
        ALPHA_W * tile[tx][r] * inv_cnt + (1.f - ALPHA_W) * cF[(size_t)c * HW + pix];
  }
}

// ---------------------------------------------------------------------------
extern "C" void kernel_launch(void* const* d_in, const int* in_sizes, int n_in,
                              void* d_out, int out_size, void* d_ws, size_t ws_size,
                              hipStream_t stream) {
  const float* cF   = (const float*)d_in[0];
  const float* sF   = (const float*)d_in[1];
  const float* cSem = (const float*)d_in[2];
  const float* sSem = (const float*)d_in[3];
  float* out = (float*)d_out;

  char* ws = (char*)d_ws;
  size_t off = 0;
  float* cFf  = (float*)(ws + off); off += (size_t)C_F * HW * 4;        // 9.44 MB
  float* sFf  = (float*)(ws + off); off += (size_t)C_F * HW * 4;        // 9.44 MB
  float* M    = (float*)(ws + off); off += (size_t)HW * HW * 4;         // 67.1 MB
  float* sFt  = (float*)(ws + off); off += (size_t)HW * C_MAIN * 4;     // 8.39 MB
  float* tmp  = (float*)(ws + off); off += (size_t)HW * C_MAIN * 4;     // 8.39 MB
  float* q    = (float*)(ws + off); off += HW * 4;
  float* rnrm = (float*)(ws + off); off += ((KPATCH + 63) / 64) * 64 * 4;
  int*   idx  = (int*)(ws + off);   off += ((KPATCH + 63) / 64) * 64 * 4;

  project_kernel<<<2 * C_F, 256, 0, stream>>>(cF, sF, cSem, sSem, cFf, sFf);
  gemm_kernel<<<dim3(64, 64), 256, 0, stream>>>(cFf, sFf, M);
  colsumsq_kernel<<<HW / 256, 256, 0, stream>>>(sFf, q);
  rnorm_kernel<<<(KPATCH + 255) / 256, 256, 0, stream>>>(q, rnrm);
  argmax_kernel<<<KPATCH, 256, 0, stream>>>(M, rnrm, idx);
  transpose_kernel<<<dim3(128, 16), dim3(32, 8), 0, stream>>>(sF, sFt);
  gather_kernel<<<HW, 256, 0, stream>>>(sFt, idx, tmp);
  blend_kernel<<<dim3(128, 16), dim3(32, 8), 0, stream>>>(tmp, cF, out);
}

// Round 2
// 392.093 us; speedup vs baseline: 1.0694x; 1.0694x over previous
//
#include <hip/hip_runtime.h>

#define HW      4096
#define WIDTH   64
#define C_MAIN  512
#define C_F     576
#define HO      62
#define KPATCH  3844   // 62*62
#define ALPHA_W 0.6f
#define SEM_W   0.5f
#define EPS_V   1e-5f

// ---------------------------------------------------------------------------
// 1. Instance-norm projection + semantic concat:  cFf/sFf [576][4096]
// ---------------------------------------------------------------------------
__global__ __launch_bounds__(256) void project_kernel(
    const float* __restrict__ cF, const float* __restrict__ sF,
    const float* __restrict__ cSem, const float* __restrict__ sSem,
    float* __restrict__ cFf, float* __restrict__ sFf) {
  int bid = blockIdx.x;            // 0..1151
  int tensor = bid / C_F;          // 0: content, 1: style
  int c = bid - tensor * C_F;
  float* dst = (tensor ? sFf : cFf) + (size_t)c * HW;
  int t = threadIdx.x;

  if (c >= C_MAIN) {               // semantic channel: just scale by 0.5
    const float* src = (tensor ? sSem : cSem) + (size_t)(c - C_MAIN) * HW;
    for (int p = t * 4; p < HW; p += 256 * 4) {
      float4 v = *(const float4*)(src + p);
      v.x *= SEM_W; v.y *= SEM_W; v.z *= SEM_W; v.w *= SEM_W;
      *(float4*)(dst + p) = v;
    }
    return;
  }

  const float* src = (tensor ? sF : cF) + (size_t)c * HW;
  float4 vals[4];
  float sum = 0.f, sumsq = 0.f;
#pragma unroll
  for (int i = 0; i < 4; ++i) {
    vals[i] = *(const float4*)(src + (i * 256 + t) * 4);
    sum   += vals[i].x + vals[i].y + vals[i].z + vals[i].w;
    sumsq += vals[i].x * vals[i].x + vals[i].y * vals[i].y +
             vals[i].z * vals[i].z + vals[i].w * vals[i].w;
  }
#pragma unroll
  for (int off = 32; off; off >>= 1) {
    sum   += __shfl_down(sum, off, 64);
    sumsq += __shfl_down(sumsq, off, 64);
  }
  __shared__ float ls[10];
  int lane = t & 63, wv = t >> 6;
  if (lane == 0) { ls[wv] = sum; ls[4 + wv] = sumsq; }
  __syncthreads();
  if (t == 0) {
    float s  = ls[0] + ls[1] + ls[2] + ls[3];
    float sq = ls[4] + ls[5] + ls[6] + ls[7];
    float mean = s / 4096.f;
    float var  = (sq - 4096.f * mean * mean) / 4095.f;   // ddof=1
    ls[8] = mean;
    ls[9] = 1.f / sqrtf(var + EPS_V);
  }
  __syncthreads();
  float mean = ls[8], rstd = ls[9];
#pragma unroll
  for (int i = 0; i < 4; ++i) {
    float4 v = vals[i];
    v.x = (v.x - mean) * rstd; v.y = (v.y - mean) * rstd;
    v.z = (v.z - mean) * rstd; v.w = (v.w - mean) * rstd;
    *(float4*)(dst + (i * 256 + t) * 4) = v;
  }
}

// ---------------------------------------------------------------------------
// 2. fp32 GEMM: M[a][u] = sum_k cFf[k][a] * sFf[k][u]   (4096x4096, K=576)
//    128x128 tile, BK=16, 256 threads, 8x8 micro-tile (4+4 split at stride 64
//    so every LDS read is the conflict-free tx*4 / ty*4 b128 pattern).
// ---------------------------------------------------------------------------
__global__ __launch_bounds__(256) void gemm_kernel(
    const float* __restrict__ A, const float* __restrict__ B,
    float* __restrict__ M) {
  __shared__ float As[16][128];
  __shared__ float Bs[16][128];
  int a0 = blockIdx.x * 128;
  int u0 = blockIdx.y * 128;
  int t = threadIdx.x;
  int tx = t & 15, ty = t >> 4;

  // staging map: 16 rows x 128 cols per operand; thread -> row t>>4, col (t&15)*8
  int srow = t >> 4;
  int scol = (t & 15) * 8;
  const float* Ag = A + (size_t)srow * HW + a0 + scol;
  const float* Bg = B + (size_t)srow * HW + u0 + scol;

  float acc[8][8] = {};
  for (int k0 = 0; k0 < C_F; k0 += 16) {
    float4 ra0 = *(const float4*)(Ag);
    float4 ra1 = *(const float4*)(Ag + 4);
    float4 rb0 = *(const float4*)(Bg);
    float4 rb1 = *(const float4*)(Bg + 4);
    Ag += (size_t)16 * HW;
    Bg += (size_t)16 * HW;
    __syncthreads();
    *(float4*)&As[srow][scol]     = ra0;
    *(float4*)&As[srow][scol + 4] = ra1;
    *(float4*)&Bs[srow][scol]     = rb0;
    *(float4*)&Bs[srow][scol + 4] = rb1;
    __syncthreads();
#pragma unroll
    for (int kk = 0; kk < 16; ++kk) {
      float a[8], b[8];
      *(float4*)&a[0] = *(const float4*)&As[kk][ty * 4];
      *(float4*)&a[4] = *(const float4*)&As[kk][64 + ty * 4];
      *(float4*)&b[0] = *(const float4*)&Bs[kk][tx * 4];
      *(float4*)&b[4] = *(const float4*)&Bs[kk][64 + tx * 4];
#pragma unroll
      for (int i = 0; i < 8; ++i)
#pragma unroll
        for (int j = 0; j < 8; ++j) acc[i][j] += a[i] * b[j];
    }
  }
#pragma unroll
  for (int i = 0; i < 8; ++i) {
    int row = a0 + (i < 4 ? ty * 4 + i : 64 + ty * 4 + (i - 4));
    float4 v0 = {acc[i][0], acc[i][1], acc[i][2], acc[i][3]};
    float4 v1 = {acc[i][4], acc[i][5], acc[i][6], acc[i][7]};
    *(float4*)(M + (size_t)row * HW + u0 + tx * 4)      = v0;
    *(float4*)(M + (size_t)row * HW + u0 + 64 + tx * 4) = v1;
  }
}

// ---------------------------------------------------------------------------
// 3a. q[u] = sum_c sFf[c][u]^2
// ---------------------------------------------------------------------------
__global__ __launch_bounds__(256) void colsumsq_kernel(
    const float* __restrict__ sFf, float* __restrict__ q) {
  int u = blockIdx.x * 256 + threadIdx.x;
  float s = 0.f;
  for (int c = 0; c < C_F; ++c) {
    float v = sFf[(size_t)c * HW + u];
    s += v * v;
  }
  q[u] = s;
}

// 3b. rnorm[k] = 1/(sqrt(3x3 box of q) + 1e-7)
__global__ __launch_bounds__(256) void rnorm_kernel(
    const float* __restrict__ q, float* __restrict__ rnorm) {
  int k = blockIdx.x * 256 + threadIdx.x;
  if (k >= KPATCH) return;
  int ky = k / HO, kx = k - ky * HO;
  float s = 0.f;
#pragma unroll
  for (int i = 0; i < 3; ++i)
#pragma unroll
    for (int j = 0; j < 3; ++j) s += q[(ky + i) * WIDTH + kx + j];
  rnorm[k] = 1.f / (sqrtf(s) + 1e-7f);
}

// ---------------------------------------------------------------------------
// 4. argmax over styles: one block per content position
// ---------------------------------------------------------------------------
__global__ __launch_bounds__(256) void argmax_kernel(
    const float* __restrict__ M, const float* __restrict__ rnorm,
    int* __restrict__ idx) {
  int bid = blockIdx.x;           // 0..3843
  int y = bid / HO, x = bid - y * HO;
  const float* base[9];
#pragma unroll
  for (int i = 0; i < 3; ++i)
#pragma unroll
    for (int j = 0; j < 3; ++j)
      base[i * 3 + j] = M + (size_t)((y + i) * WIDTH + x + j) * HW + i * WIDTH + j;

  float best = -1e30f;
  int bestk = 0;
  for (int k = threadIdx.x; k < KPATCH; k += 256) {
    int ky = k / HO;
    int u = k + 2 * ky;           // ky*64 + kx
    float s = base[0][u] + base[1][u] + base[2][u] +
              base[3][u] + base[4][u] + base[5][u] +
              base[6][u] + base[7][u] + base[8][u];
    float v = s * rnorm[k];
    if (v > best) { best = v; bestk = k; }   // strict > keeps lowest k
  }
  __shared__ float sv[256];
  __shared__ int   sk[256];
  sv[threadIdx.x] = best; sk[threadIdx.x] = bestk;
  __syncthreads();
  for (int off = 128; off; off >>= 1) {
    if (threadIdx.x < off) {
      float ov = sv[threadIdx.x + off]; int ok = sk[threadIdx.x + off];
      if (ov > sv[threadIdx.x] ||
          (ov == sv[threadIdx.x] && ok < sk[threadIdx.x])) {
        sv[threadIdx.x] = ov; sk[threadIdx.x] = ok;
      }
    }
    __syncthreads();
  }
  if (threadIdx.x == 0) idx[bid] = sk[0];
}

// ---------------------------------------------------------------------------
// 5. transpose sF [c][pix] -> sFt [pix][c]
// ---------------------------------------------------------------------------
__global__ __launch_bounds__(256) void transpose_kernel(
    const float* __restrict__ sF, float* __restrict__ sFt) {
  __shared__ float tile[32][33];
  int p0 = blockIdx.x * 32;
  int c0 = blockIdx.y * 32;
  int tx = threadIdx.x, ty = threadIdx.y;   // (32,8)
  for (int r = ty; r < 32; r += 8)
    tile[r][tx] = sF[(size_t)(c0 + r) * HW + p0 + tx];
  __syncthreads();
  for (int r = ty; r < 32; r += 8)
    sFt[(size_t)(p0 + r) * C_MAIN + c0 + tx] = tile[tx][r];
}

// ---------------------------------------------------------------------------
// 6. gather selected patches, overlap-add in [pix][c]
// ---------------------------------------------------------------------------
__global__ __launch_bounds__(256) void gather_kernel(
    const float* __restrict__ sFt, const int* __restrict__ idx,
    float* __restrict__ tmp) {
  __shared__ int srcs[9];
  __shared__ int nv;
  int pix = blockIdx.x;
  int h = pix >> 6, w = pix & 63;
  if (threadIdx.x == 0) {
    int n = 0;
    for (int i = 0; i < 3; ++i)
      for (int j = 0; j < 3; ++j) {
        int y = h - i, x = w - j;
        if (y >= 0 && y < HO && x >= 0 && x < HO) {
          int k = idx[y * HO + x];
          int ky = k / HO, kx = k - ky * HO;
          srcs[n++] = (ky + i) * WIDTH + kx + j;
        }
      }
    nv = n;
  }
  __syncthreads();
  int n = nv;
  for (int c = threadIdx.x; c < C_MAIN; c += 256) {
    float acc = 0.f;
    for (int s = 0; s < n; ++s) acc += sFt[(size_t)srcs[s] * C_MAIN + c];
    tmp[(size_t)pix * C_MAIN + c] = acc;
  }
}

// ---------------------------------------------------------------------------
// 7. blend + transpose back:  out[c][pix] = 0.6*tmp[pix][c]/cnt + 0.4*cF
// ---------------------------------------------------------------------------
__global__ __launch_bounds__(256) void blend_kernel(
    const float* __restrict__ tmp, const float* __restrict__ cF,
    float* __restrict__ out) {
  __shared__ float tile[32][33];
  int p0 = blockIdx.x * 32;
  int c0 = blockIdx.y * 32;
  int tx = threadIdx.x, ty = threadIdx.y;   // (32,8)
  for (int r = ty; r < 32; r += 8)
    tile[r][tx] = tmp[(size_t)(p0 + r) * C_MAIN + c0 + tx];
  __syncthreads();
  for (int r = ty; r < 32; r += 8) {
    int pix = p0 + tx;
    int h = pix >> 6, w = pix & 63;
    int nh = min(2, h) - max(0, h - 61) + 1;
    int nw = min(2, w) - max(0, w - 61) + 1;
    float inv_cnt = 1.f / (float)(nh * nw);
    int c = c0 + r;
    out[(size_t)c * HW + pix] =
        ALPHA_W * tile[tx][r] * inv_cnt + (1.f - ALPHA_W) * cF[(size_t)c * HW + pix];
  }
}

// ---------------------------------------------------------------------------
extern "C" void kernel_launch(void* const* d_in, const int* in_sizes, int n_in,
                              void* d_out, int out_size, void* d_ws, size_t ws_size,
                              hipStream_t stream) {
  const float* cF   = (const float*)d_in[0];
  const float* sF   = (const float*)d_in[1];
  const float* cSem = (const float*)d_in[2];
  const float* sSem = (const float*)d_in[3];
  float* out = (float*)d_out;

  char* ws = (char*)d_ws;
  size_t off = 0;
  float* cFf  = (float*)(ws + off); off += (size_t)C_F * HW * 4;        // 9.44 MB
  float* sFf  = (float*)(ws + off); off += (size_t)C_F * HW * 4;        // 9.44 MB
  float* M    = (float*)(ws + off); off += (size_t)HW * HW * 4;         // 67.1 MB
  float* sFt  = (float*)(ws + off); off += (size_t)HW * C_MAIN * 4;     // 8.39 MB
  float* tmp  = (float*)(ws + off); off += (size_t)HW * C_MAIN * 4;     // 8.39 MB
  float* q    = (float*)(ws + off); off += HW * 4;
  float* rnrm = (float*)(ws + off); off += ((KPATCH + 63) / 64) * 64 * 4;
  int*   idx  = (int*)(ws + off);   off += ((KPATCH + 63) / 64) * 64 * 4;

  project_kernel<<<2 * C_F, 256, 0, stream>>>(cF, sF, cSem, sSem, cFf, sFf);
  gemm_kernel<<<dim3(32, 32), 256, 0, stream>>>(cFf, sFf, M);
  colsumsq_kernel<<<HW / 256, 256, 0, stream>>>(sFf, q);
  rnorm_kernel<<<(KPATCH + 255) / 256, 256, 0, stream>>>(q, rnrm);
  argmax_kernel<<<KPATCH, 256, 0, stream>>>(M, rnrm, idx);
  transpose_kernel<<<dim3(128, 16), dim3(32, 8), 0, stream>>>(sF, sFt);
  gather_kernel<<<HW, 256, 0, stream>>>(sFt, idx, tmp);
  blend_kernel<<<dim3(128, 16), dim3(32, 8), 0, stream>>>(tmp, cF, out);
}

// Round 4
// 369.388 us; speedup vs baseline: 1.1351x; 1.0615x over previous
//
#include <hip/hip_runtime.h>

#define HW      4096
#define WIDTH   64
#define C_MAIN  512
#define C_F     576
#define HO      62
#define KPATCH  3844   // 62*62
#define ALPHA_W 0.6f
#define SEM_W   0.5f
#define EPS_V   1e-5f

// ---------------------------------------------------------------------------
// 1. Instance-norm projection + semantic concat:  cFf/sFf [576][4096]
// ---------------------------------------------------------------------------
__global__ __launch_bounds__(256) void project_kernel(
    const float* __restrict__ cF, const float* __restrict__ sF,
    const float* __restrict__ cSem, const float* __restrict__ sSem,
    float* __restrict__ cFf, float* __restrict__ sFf) {
  int bid = blockIdx.x;            // 0..1151
  int tensor = bid / C_F;          // 0: content, 1: style
  int c = bid - tensor * C_F;
  float* dst = (tensor ? sFf : cFf) + (size_t)c * HW;
  int t = threadIdx.x;

  if (c >= C_MAIN) {               // semantic channel: just scale by 0.5
    const float* src = (tensor ? sSem : cSem) + (size_t)(c - C_MAIN) * HW;
    for (int p = t * 4; p < HW; p += 256 * 4) {
      float4 v = *(const float4*)(src + p);
      v.x *= SEM_W; v.y *= SEM_W; v.z *= SEM_W; v.w *= SEM_W;
      *(float4*)(dst + p) = v;
    }
    return;
  }

  const float* src = (tensor ? sF : cF) + (size_t)c * HW;
  float4 vals[4];
  float sum = 0.f, sumsq = 0.f;
#pragma unroll
  for (int i = 0; i < 4; ++i) {
    vals[i] = *(const float4*)(src + (i * 256 + t) * 4);
    sum   += vals[i].x + vals[i].y + vals[i].z + vals[i].w;
    sumsq += vals[i].x * vals[i].x + vals[i].y * vals[i].y +
             vals[i].z * vals[i].z + vals[i].w * vals[i].w;
  }
#pragma unroll
  for (int off = 32; off; off >>= 1) {
    sum   += __shfl_down(sum, off, 64);
    sumsq += __shfl_down(sumsq, off, 64);
  }
  __shared__ float ls[10];
  int lane = t & 63, wv = t >> 6;
  if (lane == 0) { ls[wv] = sum; ls[4 + wv] = sumsq; }
  __syncthreads();
  if (t == 0) {
    float s  = ls[0] + ls[1] + ls[2] + ls[3];
    float sq = ls[4] + ls[5] + ls[6] + ls[7];
    float mean = s / 4096.f;
    float var  = (sq - 4096.f * mean * mean) / 4095.f;   // ddof=1
    ls[8] = mean;
    ls[9] = 1.f / sqrtf(var + EPS_V);
  }
  __syncthreads();
  float mean = ls[8], rstd = ls[9];
#pragma unroll
  for (int i = 0; i < 4; ++i) {
    float4 v = vals[i];
    v.x = (v.x - mean) * rstd; v.y = (v.y - mean) * rstd;
    v.z = (v.z - mean) * rstd; v.w = (v.w - mean) * rstd;
    *(float4*)(dst + (i * 256 + t) * 4) = v;
  }
}

// ---------------------------------------------------------------------------
// 2. fp32 GEMM: M[a][u] = sum_k cFf[k][a] * sFf[k][u]   (4096x4096, K=576)
//    128x128 tile, BK=16, 256 threads, 8x8 micro-tile.
//    Stage writes use the conflict-free stride-16B pattern (two halves at
//    +0 / +64); next-tile global loads issued right after the barrier so
//    HBM latency hides under the 16x64-FMA compute block.
// ---------------------------------------------------------------------------
__global__ __launch_bounds__(256) void gemm_kernel(
    const float* __restrict__ A, const float* __restrict__ B,
    float* __restrict__ M) {
  __shared__ float As[16][128];
  __shared__ float Bs[16][128];
  int a0 = blockIdx.x * 128;
  int u0 = blockIdx.y * 128;
  int t = threadIdx.x;
  int tx = t & 15, ty = t >> 4;

  int srow = t >> 4;           // 0..15
  int scol = (t & 15) * 4;     // stride-16B: conflict-free (round-1 verified)
  const float* Ag = A + (size_t)srow * HW + a0 + scol;
  const float* Bg = B + (size_t)srow * HW + u0 + scol;

  // prefetch K-tile 0
  float4 ra0 = *(const float4*)(Ag);
  float4 ra1 = *(const float4*)(Ag + 64);
  float4 rb0 = *(const float4*)(Bg);
  float4 rb1 = *(const float4*)(Bg + 64);

  float acc[8][8] = {};
  for (int k0 = 0; k0 < C_F; k0 += 16) {
    __syncthreads();                       // previous compute done
    *(float4*)&As[srow][scol]      = ra0;
    *(float4*)&As[srow][scol + 64] = ra1;
    *(float4*)&Bs[srow][scol]      = rb0;
    *(float4*)&Bs[srow][scol + 64] = rb1;
    __syncthreads();
    if (k0 + 16 < C_F) {                   // issue next-tile loads early
      Ag += (size_t)16 * HW;
      Bg += (size_t)16 * HW;
      ra0 = *(const float4*)(Ag);
      ra1 = *(const float4*)(Ag + 64);
      rb0 = *(const float4*)(Bg);
      rb1 = *(const float4*)(Bg + 64);
    }
#pragma unroll
    for (int kk = 0; kk < 16; ++kk) {
      float a[8], b[8];
      *(float4*)&a[0] = *(const float4*)&As[kk][ty * 4];
      *(float4*)&a[4] = *(const float4*)&As[kk][64 + ty * 4];
      *(float4*)&b[0] = *(const float4*)&Bs[kk][tx * 4];
      *(float4*)&b[4] = *(const float4*)&Bs[kk][64 + tx * 4];
#pragma unroll
      for (int i = 0; i < 8; ++i)
#pragma unroll
        for (int j = 0; j < 8; ++j) acc[i][j] += a[i] * b[j];
    }
  }
#pragma unroll
  for (int i = 0; i < 8; ++i) {
    int row = a0 + (i < 4 ? ty * 4 + i : 64 + ty * 4 + (i - 4));
    float4 v0 = {acc[i][0], acc[i][1], acc[i][2], acc[i][3]};
    float4 v1 = {acc[i][4], acc[i][5], acc[i][6], acc[i][7]};
    *(float4*)(M + (size_t)row * HW + u0 + tx * 4)      = v0;
    *(float4*)(M + (size_t)row * HW + u0 + 64 + tx * 4) = v1;
  }
}

// ---------------------------------------------------------------------------
// 3a. q[u] = sum_c sFf[c][u]^2
// ---------------------------------------------------------------------------
__global__ __launch_bounds__(256) void colsumsq_kernel(
    const float* __restrict__ sFf, float* __restrict__ q) {
  int u = blockIdx.x * 256 + threadIdx.x;
  float s = 0.f;
  for (int c = 0; c < C_F; ++c) {
    float v = sFf[(size_t)c * HW + u];
    s += v * v;
  }
  q[u] = s;
}

// 3b. rnorm[k] = 1/(sqrt(3x3 box of q) + 1e-7)
__global__ __launch_bounds__(256) void rnorm_kernel(
    const float* __restrict__ q, float* __restrict__ rnorm) {
  int k = blockIdx.x * 256 + threadIdx.x;
  if (k >= KPATCH) return;
  int ky = k / HO, kx = k - ky * HO;
  float s = 0.f;
#pragma unroll
  for (int i = 0; i < 3; ++i)
#pragma unroll
    for (int j = 0; j < 3; ++j) s += q[(ky + i) * WIDTH + kx + j];
  rnorm[k] = 1.f / (sqrtf(s) + 1e-7f);
}

// ---------------------------------------------------------------------------
// 4. argmax: one block per 2x2 content-position tile (31x31 blocks).
//    Per-position math is bit-identical to the single-position version:
//    s accumulates offsets o=(i,j) in ascending order, then *rnorm,
//    strict-> first-max per thread, lowest-k tie in the tree reduce.
// ---------------------------------------------------------------------------
__global__ __launch_bounds__(256) void argmax_kernel(
    const float* __restrict__ M, const float* __restrict__ rnorm,
    int* __restrict__ idx) {
  int y0 = blockIdx.x * 2;        // 0..60
  int x0 = blockIdx.y * 2;

  // 16 block-uniform row base pointers: rows (y0+Y)*64 + (x0+X), Y,X in 0..3
  const float* base[4][4];
#pragma unroll
  for (int Y = 0; Y < 4; ++Y)
#pragma unroll
    for (int X = 0; X < 4; ++X)
      base[Y][X] = M + (size_t)((y0 + Y) * WIDTH + x0 + X) * HW;

  float best[2][2] = {{-1e30f, -1e30f}, {-1e30f, -1e30f}};
  int bestk[2][2] = {};

  for (int k = threadIdx.x; k < KPATCH; k += 256) {
    int ky = k / HO;
    int u = k + 2 * ky;           // ky*64 + kx
    float s[2][2] = {};
#pragma unroll
    for (int i = 0; i < 3; ++i)
#pragma unroll
      for (int j = 0; j < 3; ++j) {
        int col = u + i * WIDTH + j;
#pragma unroll
        for (int py = 0; py < 2; ++py)
#pragma unroll
          for (int px = 0; px < 2; ++px)
            s[py][px] += base[py + i][px + j][col];
      }
    float rn = rnorm[k];
#pragma unroll
    for (int py = 0; py < 2; ++py)
#pragma unroll
      for (int px = 0; px < 2; ++px) {
        float v = s[py][px] * rn;
        if (v > best[py][px]) { best[py][px] = v; bestk[py][px] = k; }
      }
  }

  __shared__ float sv[256];
  __shared__ int   sk[256];
#pragma unroll
  for (int py = 0; py < 2; ++py)
    for (int px = 0; px < 2; ++px) {
      __syncthreads();
      sv[threadIdx.x] = best[py][px];
      sk[threadIdx.x] = bestk[py][px];
      __syncthreads();
      for (int off = 128; off; off >>= 1) {
        if (threadIdx.x < off) {
          float ov = sv[threadIdx.x + off]; int ok = sk[threadIdx.x + off];
          if (ov > sv[threadIdx.x] ||
              (ov == sv[threadIdx.x] && ok < sk[threadIdx.x])) {
            sv[threadIdx.x] = ov; sk[threadIdx.x] = ok;
          }
        }
        __syncthreads();
      }
      if (threadIdx.x == 0) idx[(y0 + py) * HO + x0 + px] = sk[0];
    }
}

// ---------------------------------------------------------------------------
// 5. transpose sF [c][pix] -> sFt [pix][c]
// ---------------------------------------------------------------------------
__global__ __launch_bounds__(256) void transpose_kernel(
    const float* __restrict__ sF, float* __restrict__ sFt) {
  __shared__ float tile[32][33];
  int p0 = blockIdx.x * 32;
  int c0 = blockIdx.y * 32;
  int tx = threadIdx.x, ty = threadIdx.y;   // (32,8)
  for (int r = ty; r < 32; r += 8)
    tile[r][tx] = sF[(size_t)(c0 + r) * HW + p0 + tx];
  __syncthreads();
  for (int r = ty; r < 32; r += 8)
    sFt[(size_t)(p0 + r) * C_MAIN + c0 + tx] = tile[tx][r];
}

// ---------------------------------------------------------------------------
// 6. gather selected patches, overlap-add in [pix][c]
// ---------------------------------------------------------------------------
__global__ __launch_bounds__(256) void gather_kernel(
    const float* __restrict__ sFt, const int* __restrict__ idx,
    float* __restrict__ tmp) {
  __shared__ int srcs[9];
  __shared__ int nv;
  int pix = blockIdx.x;
  int h = pix >> 6, w = pix & 63;
  if (threadIdx.x == 0) {
    int n = 0;
    for (int i = 0; i < 3; ++i)
      for (int j = 0; j < 3; ++j) {
        int y = h - i, x = w - j;
        if (y >= 0 && y < HO && x >= 0 && x < HO) {
          int k = idx[y * HO + x];
          int ky = k / HO, kx = k - ky * HO;
          srcs[n++] = (ky + i) * WIDTH + kx + j;
        }
      }
    nv = n;
  }
  __syncthreads();
  int n = nv;
  for (int c = threadIdx.x; c < C_MAIN; c += 256) {
    float acc = 0.f;
    for (int s = 0; s < n; ++s) acc += sFt[(size_t)srcs[s] * C_MAIN + c];
    tmp[(size_t)pix * C_MAIN + c] = acc;
  }
}

// ---------------------------------------------------------------------------
// 7. blend + transpose back:  out[c][pix] = 0.6*tmp[pix][c]/cnt + 0.4*cF
// ---------------------------------------------------------------------------
__global__ __launch_bounds__(256) void blend_kernel(
    const float* __restrict__ tmp, const float* __restrict__ cF,
    float* __restrict__ out) {
  __shared__ float tile[32][33];
  int p0 = blockIdx.x * 32;
  int c0 = blockIdx.y * 32;
  int tx = threadIdx.x, ty = threadIdx.y;   // (32,8)
  for (int r = ty; r < 32; r += 8)
    tile[r][tx] = tmp[(size_t)(p0 + r) * C_MAIN + c0 + tx];
  __syncthreads();
  for (int r = ty; r < 32; r += 8) {
    int pix = p0 + tx;
    int h = pix >> 6, w = pix & 63;
    int nh = min(2, h) - max(0, h - 61) + 1;
    int nw = min(2, w) - max(0, w - 61) + 1;
    float inv_cnt = 1.f / (float)(nh * nw);
    int c = c0 + r;
    out[(size_t)c * HW + pix] =
        ALPHA_W * tile[tx][r] * inv_cnt + (1.f - ALPHA_W) * cF[(size_t)c * HW + pix];
  }
}

// ---------------------------------------------------------------------------
extern "C" void kernel_launch(void* const* d_in, const int* in_sizes, int n_in,
                              void* d_out, int out_size, void* d_ws, size_t ws_size,
                              hipStream_t stream) {
  const float* cF   = (const float*)d_in[0];
  const float* sF   = (const float*)d_in[1];
  const float* cSem = (const float*)d_in[2];
  const float* sSem = (const float*)d_in[3];
  float* out = (float*)d_out;

  char* ws = (char*)d_ws;
  size_t off = 0;
  float* cFf  = (float*)(ws + off); off += (size_t)C_F * HW * 4;        // 9.44 MB
  float* sFf  = (float*)(ws + off); off += (size_t)C_F * HW * 4;        // 9.44 MB
  float* M    = (float*)(ws + off); off += (size_t)HW * HW * 4;         // 67.1 MB
  float* sFt  = (float*)(ws + off); off += (size_t)HW * C_MAIN * 4;     // 8.39 MB
  float* tmp  = (float*)(ws + off); off += (size_t)HW * C_MAIN * 4;     // 8.39 MB
  float* q    = (float*)(ws + off); off += HW * 4;
  float* rnrm = (float*)(ws + off); off += ((KPATCH + 63) / 64) * 64 * 4;
  int*   idx  = (int*)(ws + off);   off += ((KPATCH + 63) / 64) * 64 * 4;

  project_kernel<<<2 * C_F, 256, 0, stream>>>(cF, sF, cSem, sSem, cFf, sFf);
  gemm_kernel<<<dim3(32, 32), 256, 0, stream>>>(cFf, sFf, M);
  colsumsq_kernel<<<HW / 256, 256, 0, stream>>>(sFf, q);
  rnorm_kernel<<<(KPATCH + 255) / 256, 256, 0, stream>>>(q, rnrm);
  argmax_kernel<<<dim3(31, 31), 256, 0, stream>>>(M, rnrm, idx);
  transpose_kernel<<<dim3(128, 16), dim3(32, 8), 0, stream>>>(sF, sFt);
  gather_kernel<<<HW, 256, 0, stream>>>(sFt, idx, tmp);
  blend_kernel<<<dim3(128, 16), dim3(32, 8), 0, stream>>>(tmp, cF, out);
}

// Round 7
// 220.389 us; speedup vs baseline: 1.9025x; 1.6761x over previous
//
#include <hip/hip_runtime.h>
#include <hip/hip_bf16.h>

#define HW      4096
#define WIDTH   64
#define C_MAIN  512
#define C_F     576
#define HO      62
#define KPATCH  3844   // 62*62
#define ALPHA_W 0.6f
#define SEM_W   0.5f
#define EPS_V   1e-5f
#define DELTA   4e-3f

typedef __attribute__((ext_vector_type(8))) short bf16x8;
typedef __attribute__((ext_vector_type(4))) float f32x4;

// ---------------------------------------------------------------------------
// 1. Per-channel instance-norm stats: stats[tensor*512+c] = {mean, rstd, sigma}
// ---------------------------------------------------------------------------
__global__ __launch_bounds__(256) void stats_kernel(
    const float* __restrict__ cF, const float* __restrict__ sF,
    float4* __restrict__ stats) {
  int b = blockIdx.x;              // 0..1023
  int tensor = b >> 9, c = b & 511;
  const float* src = (tensor ? sF : cF) + (size_t)c * HW;
  int t = threadIdx.x;
  float sum = 0.f, sumsq = 0.f;
#pragma unroll
  for (int i = 0; i < 4; ++i) {
    float4 v = *(const float4*)(src + (i * 256 + t) * 4);
    sum   += v.x + v.y + v.z + v.w;
    sumsq += v.x * v.x + v.y * v.y + v.z * v.z + v.w * v.w;
  }
#pragma unroll
  for (int off = 32; off; off >>= 1) {
    sum   += __shfl_down(sum, off, 64);
    sumsq += __shfl_down(sumsq, off, 64);
  }
  __shared__ float ls[8];
  int lane = t & 63, wv = t >> 6;
  if (lane == 0) { ls[wv] = sum; ls[4 + wv] = sumsq; }
  __syncthreads();
  if (t == 0) {
    float s  = ls[0] + ls[1] + ls[2] + ls[3];
    float sq = ls[4] + ls[5] + ls[6] + ls[7];
    float mean = s / 4096.f;
    float var  = (sq - 4096.f * mean * mean) / 4095.f;   // ddof=1
    float sig  = sqrtf(var + EPS_V);
    stats[b] = make_float4(mean, 1.f / sig, sig, 0.f);
  }
}

// ---------------------------------------------------------------------------
// 2. Fused project + transpose + bf16 hi/lo split.
//    Outputs [p][k] ([4096][576]): content -> Ahi/Alo; style -> Bhi/Blo + sFfT fp32.
// ---------------------------------------------------------------------------
__global__ __launch_bounds__(256) void transform_kernel(
    const float* __restrict__ cF, const float* __restrict__ sF,
    const float* __restrict__ cSem, const float* __restrict__ sSem,
    const float4* __restrict__ stats,
    unsigned short* __restrict__ Ahi, unsigned short* __restrict__ Alo,
    unsigned short* __restrict__ Bhi, unsigned short* __restrict__ Blo,
    float* __restrict__ sFfT) {
  int tensor = blockIdx.z;
  int p0 = blockIdx.x * 32, k0 = blockIdx.y * 32;
  __shared__ float tile[32][33];
  int tx = threadIdx.x & 31, ty = threadIdx.x >> 5;   // 32x8
  for (int r = ty; r < 32; r += 8) {
    int ch = k0 + r;
    float x;
    if (ch < C_MAIN) {
      const float* src = tensor ? sF : cF;
      float4 st = stats[tensor * 512 + ch];
      x = (src[(size_t)ch * HW + p0 + tx] - st.x) * st.y;
    } else {
      const float* src = tensor ? sSem : cSem;
      x = SEM_W * src[(size_t)(ch - C_MAIN) * HW + p0 + tx];
    }
    tile[r][tx] = x;
  }
  __syncthreads();
  unsigned short* dhi = tensor ? Bhi : Ahi;
  unsigned short* dlo = tensor ? Blo : Alo;
  for (int r = ty; r < 32; r += 8) {
    float x = tile[tx][r];                // k = k0+tx, p = p0+r
    __hip_bfloat16 hb = __float2bfloat16(x);
    float hf = __bfloat162float(hb);
    __hip_bfloat16 lb = __float2bfloat16(x - hf);
    size_t o = (size_t)(p0 + r) * C_F + k0 + tx;
    dhi[o] = *reinterpret_cast<const unsigned short*>(&hb);
    dlo[o] = *reinterpret_cast<const unsigned short*>(&lb);
    if (tensor) sFfT[o] = x;
  }
}

// ---------------------------------------------------------------------------
// 3. MFMA GEMM: M[a][u] = hh + hl + lh  (3-term bf16 split), as round 6.
// ---------------------------------------------------------------------------
__global__ __launch_bounds__(256) void gemm_kernel(
    const unsigned short* __restrict__ Ahi, const unsigned short* __restrict__ Alo,
    const unsigned short* __restrict__ Bhi, const unsigned short* __restrict__ Blo,
    float* __restrict__ M) {
  __shared__ __align__(16) unsigned short As_hi[128 * 32];
  __shared__ __align__(16) unsigned short As_lo[128 * 32];
  __shared__ __align__(16) unsigned short Bs_hi[128 * 32];
  __shared__ __align__(16) unsigned short Bs_lo[128 * 32];
  int a0 = blockIdx.x * 128, u0 = blockIdx.y * 128;
  int t = threadIdx.x;
  int lane = t & 63, wave = t >> 6;
  int wr = wave >> 1, wc = wave & 1;
  int l15 = lane & 15, hig = lane >> 4;

  int sr = t >> 2;
  int sc = (t & 3) * 8;
  const unsigned short* Ag0 = Ahi + (size_t)(a0 + sr) * C_F + sc;
  const unsigned short* Ag1 = Alo + (size_t)(a0 + sr) * C_F + sc;
  const unsigned short* Bg0 = Bhi + (size_t)(u0 + sr) * C_F + sc;
  const unsigned short* Bg1 = Blo + (size_t)(u0 + sr) * C_F + sc;
  const size_t rstep = (size_t)64 * C_F;

  uint4 pah0 = *(const uint4*)(Ag0), pah1 = *(const uint4*)(Ag0 + rstep);
  uint4 pal0 = *(const uint4*)(Ag1), pal1 = *(const uint4*)(Ag1 + rstep);
  uint4 pbh0 = *(const uint4*)(Bg0), pbh1 = *(const uint4*)(Bg0 + rstep);
  uint4 pbl0 = *(const uint4*)(Bg1), pbl1 = *(const uint4*)(Bg1 + rstep);

  f32x4 zero4 = {0.f, 0.f, 0.f, 0.f};
  f32x4 acc[4][4];
#pragma unroll
  for (int m = 0; m < 4; ++m)
#pragma unroll
    for (int n = 0; n < 4; ++n) acc[m][n] = zero4;

  int lw = sr * 4 + (t & 3);
  for (int k0 = 0; k0 < C_F; k0 += 32) {
    __syncthreads();
    ((uint4*)As_hi)[lw] = pah0; ((uint4*)As_hi)[lw + 256] = pah1;
    ((uint4*)As_lo)[lw] = pal0; ((uint4*)As_lo)[lw + 256] = pal1;
    ((uint4*)Bs_hi)[lw] = pbh0; ((uint4*)Bs_hi)[lw + 256] = pbh1;
    ((uint4*)Bs_lo)[lw] = pbl0; ((uint4*)Bs_lo)[lw + 256] = pbl1;
    __syncthreads();
    if (k0 + 32 < C_F) {
      Ag0 += 32; Ag1 += 32; Bg0 += 32; Bg1 += 32;
      pah0 = *(const uint4*)(Ag0); pah1 = *(const uint4*)(Ag0 + rstep);
      pal0 = *(const uint4*)(Ag1); pal1 = *(const uint4*)(Ag1 + rstep);
      pbh0 = *(const uint4*)(Bg0); pbh1 = *(const uint4*)(Bg0 + rstep);
      pbl0 = *(const uint4*)(Bg1); pbl1 = *(const uint4*)(Bg1 + rstep);
    }
    bf16x8 bh[4], bl[4];
#pragma unroll
    for (int n = 0; n < 4; ++n) {
      int brow = wc * 64 + n * 16 + l15;
      bh[n] = *(const bf16x8*)&Bs_hi[brow * 32 + hig * 8];
      bl[n] = *(const bf16x8*)&Bs_lo[brow * 32 + hig * 8];
    }
#pragma unroll
    for (int m = 0; m < 4; ++m) {
      int arow = wr * 64 + m * 16 + l15;
      bf16x8 ah = *(const bf16x8*)&As_hi[arow * 32 + hig * 8];
      bf16x8 al = *(const bf16x8*)&As_lo[arow * 32 + hig * 8];
#pragma unroll
      for (int n = 0; n < 4; ++n) {
        acc[m][n] = __builtin_amdgcn_mfma_f32_16x16x32_bf16(ah, bh[n], acc[m][n], 0, 0, 0);
        acc[m][n] = __builtin_amdgcn_mfma_f32_16x16x32_bf16(ah, bl[n], acc[m][n], 0, 0, 0);
        acc[m][n] = __builtin_amdgcn_mfma_f32_16x16x32_bf16(al, bh[n], acc[m][n], 0, 0, 0);
      }
    }
  }
#pragma unroll
  for (int m = 0; m < 4; ++m) {
    int row = a0 + wr * 64 + m * 16 + hig * 4;
#pragma unroll
    for (int n = 0; n < 4; ++n) {
      int col = u0 + wc * 64 + n * 16 + l15;
#pragma unroll
      for (int r = 0; r < 4; ++r)
        M[(size_t)(row + r) * HW + col] = acc[m][n][r];
    }
  }
}

// ---------------------------------------------------------------------------
// 4a. q[u] = sum_k sFfT[u][k]^2   (one wave per row)
// ---------------------------------------------------------------------------
__global__ __launch_bounds__(256) void colsumsq_kernel(
    const float* __restrict__ sFfT, float* __restrict__ q) {
  int row = blockIdx.x * 4 + (threadIdx.x >> 6);
  int lane = threadIdx.x & 63;
  const float* r = sFfT + (size_t)row * C_F;
  float s = 0.f;
  for (int i = lane; i < C_F; i += 64) { float v = r[i]; s += v * v; }
#pragma unroll
  for (int off = 32; off; off >>= 1) s += __shfl_down(s, off, 64);
  if (lane == 0) q[row] = s;
}

// 4b. rnorm[k] = 1/(sqrt(3x3 box of q) + 1e-7)
__global__ __launch_bounds__(256) void rnorm_kernel(
    const float* __restrict__ q, float* __restrict__ rnorm) {
  int k = blockIdx.x * 256 + threadIdx.x;
  if (k >= KPATCH) return;
  int ky = k / HO, kx = k - ky * HO;
  float s = 0.f;
#pragma unroll
  for (int i = 0; i < 3; ++i)
#pragma unroll
    for (int j = 0; j < 3; ++j) s += q[(ky + i) * WIDTH + kx + j];
  rnorm[k] = 1.f / (sqrtf(s) + 1e-7f);
}

// ---------------------------------------------------------------------------
// 5. argmax with exact-rescoring rescue. One block per 2x2 positions.
//    Approx scores from bf16-split M; any candidate within DELTA of the
//    approx max gets an exact fp32 rescore from the features.
// ---------------------------------------------------------------------------
__global__ __launch_bounds__(256) void argmax_kernel(
    const float* __restrict__ M, const float* __restrict__ rnorm,
    const float* __restrict__ sFfT,
    const float* __restrict__ cF, const float* __restrict__ cSem,
    const float4* __restrict__ stats,
    int* __restrict__ idx) {
  int y0 = blockIdx.x * 2, x0 = blockIdx.y * 2;
  int t = threadIdx.x;

  const float* base[4][4];
#pragma unroll
  for (int Y = 0; Y < 4; ++Y)
#pragma unroll
    for (int X = 0; X < 4; ++X)
      base[Y][X] = M + (size_t)((y0 + Y) * WIDTH + x0 + X) * HW;

  float v1[2][2], v2[2][2];
  int   k1[2][2], k2[2][2];
#pragma unroll
  for (int py = 0; py < 2; ++py)
#pragma unroll
    for (int px = 0; px < 2; ++px) {
      v1[py][px] = -1e30f; v2[py][px] = -1e30f;
      k1[py][px] = 0;      k2[py][px] = 0;
    }

  for (int k = t; k < KPATCH; k += 256) {
    int ky = k / HO;
    int u = k + 2 * ky;           // ky*64 + kx
    float s[2][2] = {};
#pragma unroll
    for (int i = 0; i < 3; ++i)
#pragma unroll
      for (int j = 0; j < 3; ++j) {
        int col = u + i * WIDTH + j;
#pragma unroll
        for (int py = 0; py < 2; ++py)
#pragma unroll
          for (int px = 0; px < 2; ++px)
            s[py][px] += base[py + i][px + j][col];
      }
    float rn = rnorm[k];
#pragma unroll
    for (int py = 0; py < 2; ++py)
#pragma unroll
      for (int px = 0; px < 2; ++px) {
        float v = s[py][px] * rn;
        if (v > v1[py][px]) {
          v2[py][px] = v1[py][px]; k2[py][px] = k1[py][px];
          v1[py][px] = v;          k1[py][px] = k;
        } else if (v > v2[py][px]) {
          v2[py][px] = v;          k2[py][px] = k;
        }
      }
  }

  __shared__ float sv[256];
  __shared__ int   sk[256];
  __shared__ float redf[256];
  __shared__ float cpatch[9 * C_F];
  __shared__ int   candList[64];
  __shared__ int   candN;
  __shared__ float bestE;
  __shared__ int   bestK;

#pragma unroll
  for (int py = 0; py < 2; ++py)
    for (int px = 0; px < 2; ++px) {
      // ---- reduce approx best ----
      __syncthreads();
      sv[t] = v1[py][px]; sk[t] = k1[py][px];
      __syncthreads();
      for (int off = 128; off; off >>= 1) {
        if (t < off) {
          float ov = sv[t + off]; int ok = sk[t + off];
          if (ov > sv[t] || (ov == sv[t] && ok < sk[t])) { sv[t] = ov; sk[t] = ok; }
        }
        __syncthreads();
      }
      float vbest = sv[0];
      int   kbest = sk[0];
      float thr = vbest - DELTA;
      if (t == 0) candN = 0;
      __syncthreads();

      // ---- collect candidates within DELTA of vbest ----
      if (v2[py][px] >= thr) {
        // rare: this thread may own >=2 near-max k's -> rescan its own 16 k's
        for (int k = t; k < KPATCH; k += 256) {
          int ky = k / HO;
          int u = k + 2 * ky;
          float s = 0.f;
#pragma unroll
          for (int i = 0; i < 3; ++i)
#pragma unroll
            for (int j = 0; j < 3; ++j)
              s += base[py + i][px + j][u + i * WIDTH + j];
          float v = s * rnorm[k];
          if (v >= thr && k != kbest) {
            int sl = atomicAdd(&candN, 1);
            if (sl < 64) candList[sl] = k;
          }
        }
      } else if (v1[py][px] >= thr && k1[py][px] != kbest) {
        int sl = atomicAdd(&candN, 1);
        if (sl < 64) candList[sl] = k1[py][px];
      }
      __syncthreads();
      int nc = min(candN, 64);
      if (nc == 0) {               // unique max by > DELTA margin: exact winner
        if (t == 0) idx[(y0 + py) * HO + x0 + px] = kbest;
        continue;
      }

      // ---- exact rescue: stage content patch in LDS ----
      int y = y0 + py, x = x0 + px;
      for (int f = t; f < 9 * C_F; f += 256) {
        int ij = f / C_F, c = f - ij * C_F;
        int pp = (y + ij / 3) * WIDTH + x + ij % 3;
        float cv;
        if (c < C_MAIN) {
          float4 st = stats[c];
          cv = (cF[(size_t)c * HW + pp] - st.x) * st.y;
        } else {
          cv = SEM_W * cSem[(size_t)(c - C_MAIN) * HW + pp];
        }
        cpatch[f] = cv;
      }
      __syncthreads();
      if (t == 0) { bestE = -1e30f; bestK = 0x7fffffff; }
      __syncthreads();

      for (int ci = -1; ci < nc; ++ci) {
        int k = (ci < 0) ? kbest : candList[ci];
        int ky = k / HO, kx = k - ky * HO;
        float part = 0.f;
        for (int f = t; f < 9 * C_F; f += 256) {
          int ij = f / C_F, c = f - ij * C_F;
          int sp = (ky + ij / 3) * WIDTH + kx + ij % 3;
          part += cpatch[f] * sFfT[(size_t)sp * C_F + c];
        }
        redf[t] = part;
        __syncthreads();
        for (int off = 128; off; off >>= 1) {
          if (t < off) redf[t] += redf[t + off];
          __syncthreads();
        }
        if (t == 0) {
          float e = redf[0] * rnorm[k];
          if (e > bestE || (e == bestE && k < bestK)) { bestE = e; bestK = k; }
        }
        __syncthreads();
      }
      if (t == 0) idx[(y0 + py) * HO + x0 + px] = bestK;
    }
}

// ---------------------------------------------------------------------------
// 6. gather selected patches (projected style), overlap-add in [pix][c]
// ---------------------------------------------------------------------------
__global__ __launch_bounds__(256) void gather_kernel(
    const float* __restrict__ sFfT, const int* __restrict__ idx,
    float* __restrict__ tmp) {
  __shared__ int srcs[9];
  __shared__ int nv;
  int pix = blockIdx.x;
  int h = pix >> 6, w = pix & 63;
  if (threadIdx.x == 0) {
    int n = 0;
    for (int i = 0; i < 3; ++i)
      for (int j = 0; j < 3; ++j) {
        int y = h - i, x = w - j;
        if (y >= 0 && y < HO && x >= 0 && x < HO) {
          int k = idx[y * HO + x];
          int ky = k / HO, kx = k - ky * HO;
          srcs[n++] = (ky + i) * WIDTH + kx + j;
        }
      }
    nv = n;
  }
  __syncthreads();
  int n = nv;
  for (int c = threadIdx.x; c < C_MAIN; c += 256) {
    float acc = 0.f;
    for (int s = 0; s < n; ++s) acc += sFfT[(size_t)srcs[s] * C_F + c];
    tmp[(size_t)pix * C_MAIN + c] = acc;
  }
}

// ---------------------------------------------------------------------------
// 7. blend + un-project + transpose back:
//    out[c][pix] = 0.6*(sigma_c * tmp/cnt + mu_c) + 0.4*cF
// ---------------------------------------------------------------------------
__global__ void blend_kernel(
    const float* __restrict__ tmp, const float* __restrict__ cF,
    const float4* __restrict__ stats, float* __restrict__ out) {
  __shared__ float tile[32][33];
  int p0 = blockIdx.x * 32;
  int c0 = blockIdx.y * 32;
  int tx = threadIdx.x, ty = threadIdx.y;   // (32,8)
  for (int r = ty; r < 32; r += 8)
    tile[r][tx] = tmp[(size_t)(p0 + r) * C_MAIN + c0 + tx];
  __syncthreads();
  for (int r = ty; r < 32; r += 8) {
    int pix = p0 + tx;
    int h = pix >> 6, w = pix & 63;
    int nh = min(2, h) - max(0, h - 61) + 1;
    int nw = min(2, w) - max(0, w - 61) + 1;
    float inv_cnt = 1.f / (float)(nh * nw);
    int c = c0 + r;
    float4 st = stats[512 + c];              // style channel stats
    float recon = st.z * (tile[tx][r] * inv_cnt) + st.x;
    out[(size_t)c * HW + pix] =
        ALPHA_W * recon + (1.f - ALPHA_W) * cF[(size_t)c * HW + pix];
  }
}

// ---------------------------------------------------------------------------
// Workspace (total 95.5 MB, < proven-safe 102.8 MB):
//   [0        , 18874368) Ahi|Alo|Bhi|Blo  (transform -> gemm)
//       tmp overlays [0, 8388608)          (gather -> blend)
//   [18874368 , 85983232) M                (gemm -> argmax)
//   [85983232 , 95420416) sFfT fp32        (transform -> gather)
//   [95420416 , 95485952) q | rnrm | idx | stats (16K each)
// ---------------------------------------------------------------------------
extern "C" void kernel_launch(void* const* d_in, const int* in_sizes, int n_in,
                              void* d_out, int out_size, void* d_ws, size_t ws_size,
                              hipStream_t stream) {
  const float* cF   = (const float*)d_in[0];
  const float* sF   = (const float*)d_in[1];
  const float* cSem = (const float*)d_in[2];
  const float* sSem = (const float*)d_in[3];
  float* out = (float*)d_out;

  char* ws = (char*)d_ws;
  unsigned short* Ahi = (unsigned short*)ws;
  unsigned short* Alo = Ahi + (size_t)HW * C_F;
  unsigned short* Bhi = Alo + (size_t)HW * C_F;
  unsigned short* Blo = Bhi + (size_t)HW * C_F;
  float* tmp  = (float*)ws;                      // after gemm
  float* M    = (float*)(ws + 18874368);
  float* sFfT = (float*)(ws + 85983232);
  float* q    = (float*)(ws + 95420416);
  float* rnrm = (float*)(ws + 95420416 + 16384);
  int*   idx  = (int*)  (ws + 95420416 + 32768);
  float4* stats = (float4*)(ws + 95420416 + 49152);

  stats_kernel<<<1024, 256, 0, stream>>>(cF, sF, stats);
  transform_kernel<<<dim3(HW / 32, C_F / 32, 2), 256, 0, stream>>>(
      cF, sF, cSem, sSem, stats, Ahi, Alo, Bhi, Blo, sFfT);
  colsumsq_kernel<<<HW / 4, 256, 0, stream>>>(sFfT, q);
  rnorm_kernel<<<(KPATCH + 255) / 256, 256, 0, stream>>>(q, rnrm);
  gemm_kernel<<<dim3(32, 32), 256, 0, stream>>>(Ahi, Alo, Bhi, Blo, M);
  argmax_kernel<<<dim3(31, 31), 256, 0, stream>>>(M, rnrm, sFfT, cF, cSem, stats, idx);
  gather_kernel<<<HW, 256, 0, stream>>>(sFfT, idx, tmp);
  blend_kernel<<<dim3(128, 16), dim3(32, 8), 0, stream>>>(tmp, cF, stats, out);
}